// Round 7
// baseline (573.950 us; speedup 1.0000x reference)
//
#include <hip/hip_runtime.h>

typedef unsigned short u16;
using bf16x8 = __attribute__((ext_vector_type(8))) short;
using f32x4  = __attribute__((ext_vector_type(4))) float;

#define ATTN_NEG (-3.0e38f)

__device__ __forceinline__ u16 f2bf_rne(float f) {
  unsigned int u = __float_as_uint(f);
  u += 0x7fffu + ((u >> 16) & 1u);
  return (u16)(u >> 16);
}

__device__ __forceinline__ void load_lds16(const u16* g, u16* l) {
  using gp = const __attribute__((address_space(1))) unsigned int*;
  using lp = __attribute__((address_space(3))) unsigned int*;
  __builtin_amdgcn_global_load_lds((gp)g, (lp)l, 16, 0, 0);
}

// ---------------- fused prep: x convert + 4 weight transposes ----------------
__device__ __forceinline__ void transpose_body(const float* __restrict__ in,
                                               u16* __restrict__ out, int K, int N,
                                               int bx, int by, int tid) {
  __shared__ float tile[32][33];
  int tx = tid & 31, ty = tid >> 5;  // 32 x 8
  int x0 = bx * 32, y0 = by * 32;
  #pragma unroll
  for (int i = 0; i < 32; i += 8)
    tile[ty + i][tx] = in[(size_t)(y0 + ty + i) * N + x0 + tx];
  __syncthreads();
  #pragma unroll
  for (int i = 0; i < 32; i += 8)
    out[(size_t)(x0 + ty + i) * K + y0 + tx] = f2bf_rne(tile[tx][ty + i]);
}

__global__ __launch_bounds__(256) void prep_kernel(const float* __restrict__ x,
                                                   const float* __restrict__ wq,
                                                   const float* __restrict__ wk,
                                                   const float* __restrict__ wv,
                                                   const float* __restrict__ wo,
                                                   u16* xb, u16* wqt, u16* wkt, u16* wvt,
                                                   u16* wot) {
  int bid = blockIdx.x, tid = threadIdx.x;
  if (bid < 8192) {
    int i = bid * 1024 + tid * 4;
    float4 v = *(const float4*)(x + i);
    u16* p = xb + i;
    p[0] = f2bf_rne(v.x); p[1] = f2bf_rne(v.y); p[2] = f2bf_rne(v.z); p[3] = f2bf_rne(v.w);
  } else if (bid < 12288) {
    int t = bid - 8192;
    transpose_body(wq, wqt, 2048, 2048, t & 63, t >> 6, tid);
  } else if (bid < 13312) {
    int t = bid - 12288;
    transpose_body(wk, wkt, 2048, 512, t & 15, t >> 4, tid);
  } else if (bid < 14336) {
    int t = bid - 13312;
    transpose_body(wv, wvt, 2048, 512, t & 15, t >> 4, tid);
  } else {
    int t = bid - 14336;
    transpose_body(wo, wot, 2048, 2048, t & 63, t >> 6, tid);
  }
}

// ---------------- GEMM v2: BK=64 (two m97-layout 32-col halves per step) ----------------
// C[M,N] = A[M,K] * Bt[N,K]^T
// MODE 0: bf16. MODE 1: bf16 transposed k-permuted (V^T). MODE 2: fp32. MODE 3: bf16*kappa (Q).
// LDS: As/Bs each [2 halves][128 rows][32 cols] = 16 KB; half h layout identical to m97.
template <int MODE>
__device__ __forceinline__ void gemm_tile(const u16* __restrict__ A, const u16* __restrict__ Bt,
                                          void* __restrict__ Cv, int M, int N, int K,
                                          int bx, int by, char* smem) {
  u16* As = (u16*)smem;            // [2][128][32]
  u16* Bs = (u16*)(smem + 16384);  // [2][128][32]
  const int tid  = threadIdx.x;
  const int wave = tid >> 6, lane = tid & 63;
  const int quad = lane >> 4, l16 = lane & 15;
  const int m0 = by * 128, n0 = bx * 128;
  const int wm = (wave >> 1) * 64, wn = (wave & 1) * 64;
  f32x4 acc[4][4] = {};

  const int srow = lane >> 2;        // 0..15
  const int scol = (lane & 3) << 3;  // 0,8,16,24

  for (int k0 = 0; k0 < K; k0 += 64) {
    __syncthreads();
    #pragma unroll
    for (int h = 0; h < 2; ++h)
      #pragma unroll
      for (int i = 0; i < 2; ++i) {
        const int row = wave * 16 + i * 64;  // + srow per lane
        load_lds16(A  + (size_t)(m0 + row + srow) * K + k0 + h * 32 + scol,
                   As + h * 4096 + row * 32);
        load_lds16(Bt + (size_t)(n0 + row + srow) * K + k0 + h * 32 + scol,
                   Bs + h * 4096 + row * 32);
      }
    __syncthreads();
    #pragma unroll
    for (int h = 0; h < 2; ++h) {
      bf16x8 af[4], bfr[4];
      #pragma unroll
      for (int i = 0; i < 4; ++i) {
        af[i]  = *(const bf16x8*)(As + h * 4096 + (wm + i * 16 + l16) * 32 + quad * 8);
        bfr[i] = *(const bf16x8*)(Bs + h * 4096 + (wn + i * 16 + l16) * 32 + quad * 8);
      }
      #pragma unroll
      for (int mi = 0; mi < 4; ++mi)
        #pragma unroll
        for (int ni = 0; ni < 4; ++ni)
          acc[mi][ni] =
              __builtin_amdgcn_mfma_f32_16x16x32_bf16(af[mi], bfr[ni], acc[mi][ni], 0, 0, 0);
    }
  }

  if constexpr (MODE == 0 || MODE == 3) {
    const float sc = (MODE == 3) ? 0.12751742f : 1.0f;  // log2(e)/sqrt(128)
    u16* Cb = (u16*)Cv;
    #pragma unroll
    for (int mi = 0; mi < 4; ++mi)
      #pragma unroll
      for (int ni = 0; ni < 4; ++ni) {
        int row = m0 + wm + mi * 16 + quad * 4;
        int col = n0 + wn + ni * 16 + l16;
        #pragma unroll
        for (int r = 0; r < 4; ++r)
          Cb[(size_t)(row + r) * N + col] = f2bf_rne(acc[mi][ni][r] * sc);
      }
  } else if constexpr (MODE == 1) {
    // V^T with k-permuted 32-chunks: pos(k) = ((k&15)>>2)*8 + ((k>>4)&1)*4 + (k&3)
    u16* Cb = (u16*)Cv;
    #pragma unroll
    for (int mi = 0; mi < 4; ++mi)
      #pragma unroll
      for (int ni = 0; ni < 4; ++ni) {
        int col = n0 + wn + ni * 16 + l16;
        #pragma unroll
        for (int r = 0; r < 4; ++r) {
          int row = m0 + wm + mi * 16 + quad * 4 + r;
          int bb = row >> 11, s = row & 2047;
          int c = s & 31;
          int cp = ((c & 15) >> 2) * 8 + ((c >> 4) & 1) * 4 + (c & 3);
          Cb[((size_t)(bb * 512 + col)) * 2048 + (s & ~31) + cp] = f2bf_rne(acc[mi][ni][r]);
        }
      }
  } else {
    float* Cf = (float*)Cv;
    #pragma unroll
    for (int mi = 0; mi < 4; ++mi)
      #pragma unroll
      for (int ni = 0; ni < 4; ++ni) {
        int row = m0 + wm + mi * 16 + quad * 4;
        int col = n0 + wn + ni * 16 + l16;
        #pragma unroll
        for (int r = 0; r < 4; ++r)
          Cf[(size_t)(row + r) * N + col] = acc[mi][ni][r];
      }
  }
}

__global__ __launch_bounds__(256) void qkv_gemm(const u16* xb, const u16* wqt, const u16* wkt,
                                                const u16* wvt, u16* Qb, u16* Kb, u16* Vt) {
  extern __shared__ char smem[];
  int bx = blockIdx.x, by = blockIdx.y;
  if (bx < 16)
    gemm_tile<3>(xb, wqt, Qb, 4096, 2048, 2048, bx, by, smem);
  else if (bx < 20)
    gemm_tile<0>(xb, wkt, Kb, 4096, 512, 2048, bx - 16, by, smem);
  else
    gemm_tile<1>(xb, wvt, Vt, 4096, 512, 2048, bx - 20, by, smem);
}

template <int MODE>
__global__ __launch_bounds__(256) void gemm_kernel(const u16* A, const u16* Bt, void* C,
                                                   int M, int N, int K) {
  extern __shared__ char smem[];
  gemm_tile<MODE>(A, Bt, C, M, N, K, blockIdx.x, blockIdx.y, smem);
}

// ---------------- flash attention: 64-key steps, V in registers ----------------
// R6 analysis: T_step ~5775cyc, >52% = LDS reads (8 waves x identical 32KB K+V tile =
// 256KB/step at 85B/cyc). Fix: V never touches LDS. Each lane loads its own 16B V
// fragments from global (L1/L2-resident: all 8 waves/CU share the tile) with a FULL-STEP
// prefetch distance (vvA/vvB parity buffers) so L2/L3 latency hides under compute.
// K keeps the LDS double-buffer, but with raw s_barrier + counted vmcnt(16) (R3-proven)
// so the V prefetch is never drained at a barrier.
// Per-step issue order (pinned): [vmcnt(16): K-stage(s) done, vv(s) in flight] ->
// s_barrier -> K-stage(s+1) -> sched_barrier -> V-prefetch(s+1) -> compute(s).

__device__ __forceinline__ void stage_k64(const u16* __restrict__ Kg, int kt0,
                                          u16* __restrict__ kbuf, int wave, int quad, int l16) {
  #pragma unroll
  for (int c = 0; c < 2; ++c)
    #pragma unroll
    for (int h = 0; h < 2; ++h)
      load_lds16(Kg + (size_t)(kt0 + 32 * c + h * 16 + l16) * 512 + wave * 32 + quad * 8,
                 kbuf + c * 4096 + (wave * 2 + h) * 512);
}

__device__ __forceinline__ void load_v64(const u16* __restrict__ Vg, int kt0,
                                         int quad, int l16, bf16x8 (&vv)[16]) {
  #pragma unroll
  for (int c = 0; c < 2; ++c)
    #pragma unroll
    for (int f = 0; f < 8; ++f)
      vv[c * 8 + f] = *(const bf16x8*)(Vg + (size_t)(16 * f + l16) * 2048 + kt0 + 32 * c + quad * 8);
}

template <bool MASKED>
__device__ __forceinline__ void attn_compute64(const u16* __restrict__ kbuf,
                                               const bf16x8 (&vv)[16],
                                               int kt0, int q0w, int quad, int l16,
                                               const bf16x8 (&qf)[4], f32x4 (&o)[8],
                                               float& l_lane) {
  const int slot = (quad * 16 + l16) * 8;  // lane*16B
  #pragma unroll
  for (int c = 0; c < 2; ++c) {
    const int kb = kt0 + 32 * c;
    if (MASKED && kb > q0w + 15) break;  // wave-uniform: sub-tile fully above diagonal

    bf16x8 kf[8];
    #pragma unroll
    for (int kk = 0; kk < 8; ++kk)
      kf[kk] = *(const bf16x8*)(kbuf + c * 4096 + kk * 512 + slot);

    f32x4 sa[2] = {};
    __builtin_amdgcn_s_setprio(1);
    #pragma unroll
    for (int h = 0; h < 2; ++h)
      #pragma unroll
      for (int ks = 0; ks < 4; ++ks)
        sa[h] = __builtin_amdgcn_mfma_f32_16x16x32_bf16(kf[ks * 2 + h], qf[ks], sa[h], 0, 0, 0);
    __builtin_amdgcn_s_setprio(0);

    // P packed as x32 A-fragment: element h*4+r sits at contraction slot quad*8+h*4+r,
    // which is exactly perm position cp(k) of k = 16h + quad*4 + r (the Vt layout).
    bf16x8 pc;
    #pragma unroll
    for (int h = 0; h < 2; ++h)
      #pragma unroll
      for (int r = 0; r < 4; ++r) {
        float s = sa[h][r];
        if (MASKED) {
          int kpos = kb + 16 * h + quad * 4 + r;
          s = (kpos <= q0w + l16) ? s : ATTN_NEG;
        }
        float p = __builtin_amdgcn_exp2f(s);
        l_lane += p;
        pc[h * 4 + r] = (short)f2bf_rne(p);
      }

    __builtin_amdgcn_s_setprio(1);
    #pragma unroll
    for (int f = 0; f < 8; ++f)
      o[f] = __builtin_amdgcn_mfma_f32_16x16x32_bf16(pc, vv[c * 8 + f], o[f], 0, 0, 0);
    __builtin_amdgcn_s_setprio(0);
  }
}

// One step of the pipeline; VVC = current V regs, VVN = next-step V regs.
#define ATTN_STEP(VVC, VVN)                                                          \
  {                                                                                  \
    asm volatile("s_waitcnt vmcnt(16)" ::: "memory"); /* K-stage(s) done */          \
    __builtin_amdgcn_s_barrier();                     /* kbuf[s&1] visible */        \
    const int sn = (s + 1 < nsteps) ? s + 1 : s;      /* tail: dummy re-stage */     \
    stage_k64(Kg, sn * 64, Kt[(s + 1) & 1], wave, quad, l16);                        \
    __builtin_amdgcn_sched_barrier(0);                /* keep stage before vv */     \
    load_v64(Vg, sn * 64, quad, l16, VVN);                                           \
    if (s + 1 < nsteps)                                                              \
      attn_compute64<false>(Kt[s & 1], VVC, s * 64, q0w, quad, l16, qf, o, l_lane);  \
    else                                                                             \
      attn_compute64<true>(Kt[s & 1], VVC, s * 64, q0w, quad, l16, qf, o, l_lane);   \
  }

// Blocks: (pair 0..15, head, b); 4 waves x 16 q-rows = 64-row tiles; pair p does tiles p
// and 31-p -> uniform 33 steps; 512 blocks = 2 blocks/CU.
__global__ __launch_bounds__(256, 2) void attn_kernel(const u16* __restrict__ Qb,
                                                      const u16* __restrict__ Kb,
                                                      const u16* __restrict__ Vt,
                                                      u16* __restrict__ Ob) {
  constexpr int S = 2048;
  const int b = blockIdx.z, h = blockIdx.y, g = h >> 2, tp = blockIdx.x;
  const int tid = threadIdx.x;
  const int wave = tid >> 6, lane = tid & 63, quad = lane >> 4, l16 = lane & 15;
  __shared__ alignas(16) u16 Kt[2][8192];
  __shared__ float lbuf[4][16];

  const u16* Kg = Kb + (size_t)b * S * 512 + g * 128;
  const u16* Vg = Vt + (size_t)(b * 512 + g * 128) * 2048;

  #pragma unroll
  for (int half = 0; half < 2; ++half) {
    const int tile = (half == 0) ? tp : 31 - tp;
    const int wrow = (half == 0) ? wave : 3 - wave;  // balance diag-step partial work
    const int q0w = tile * 64 + wrow * 16;
    const int nsteps = tile + 1;  // 64-key steps

    bf16x8 qf[4];
    const u16* qrow = Qb + (size_t)(b * S + q0w + l16) * 2048 + h * 128 + quad * 8;
    #pragma unroll
    for (int ks = 0; ks < 4; ++ks) qf[ks] = *(const bf16x8*)(qrow + ks * 32);

    f32x4 o[8] = {};
    float l_lane = 0.f;
    bf16x8 vvA[16], vvB[16];

    __syncthreads();  // previous half's readers done + vmcnt drained (clean bookkeeping)
    stage_k64(Kg, 0, Kt[0], wave, quad, l16);
    __builtin_amdgcn_sched_barrier(0);
    load_v64(Vg, 0, quad, l16, vvA);

    for (int s = 0; s < nsteps;) {
      ATTN_STEP(vvA, vvB);
      ++s;
      if (s == nsteps) break;
      ATTN_STEP(vvB, vvA);
      ++s;
    }

    // total l per q=l16: sum over quads
    float lt = l_lane + __shfl_xor(l_lane, 16);
    lt += __shfl_xor(lt, 32);
    if (quad == 0) lbuf[wave][l16] = lt;
    __builtin_amdgcn_wave_barrier();
    float il[4];
    #pragma unroll
    for (int r = 0; r < 4; ++r) il[r] = 1.f / lbuf[wave][quad * 4 + r];

    u16* orow = Ob + (size_t)(b * S + q0w + quad * 4) * 2048 + h * 128 + l16;
    #pragma unroll
    for (int f = 0; f < 8; ++f)
      #pragma unroll
      for (int r = 0; r < 4; ++r)
        orow[(size_t)r * 2048 + f * 16] = f2bf_rne(o[f][r] * il[r]);
  }
}

extern "C" void kernel_launch(void* const* d_in, const int* in_sizes, int n_in,
                              void* d_out, int out_size, void* d_ws, size_t ws_size,
                              hipStream_t stream) {
  const float* x  = (const float*)d_in[0];
  const float* wq = (const float*)d_in[1];
  const float* wk = (const float*)d_in[2];
  const float* wv = (const float*)d_in[3];
  const float* wo = (const float*)d_in[4];
  float* out = (float*)d_out;
  char* ws = (char*)d_ws;

  u16* xb  = (u16*)(ws);
  u16* wqt = (u16*)(ws + 16777216);
  u16* wkt = (u16*)(ws + 25165824);
  u16* wvt = (u16*)(ws + 27262976);
  u16* wot = (u16*)(ws + 29360128);
  u16* Qb  = (u16*)(ws + 37748736);
  u16* Kb  = (u16*)(ws + 54525952);
  u16* Vt  = (u16*)(ws + 58720256);
  u16* Ab  = (u16*)(ws + 62914560);

  prep_kernel<<<18432, 256, 0, stream>>>(x, wq, wk, wv, wo, xb, wqt, wkt, wvt, wot);
  qkv_gemm<<<dim3(24, 32), 256, 32768, stream>>>(xb, wqt, wkt, wvt, Qb, Kb, Vt);
  attn_kernel<<<dim3(16, 16, 2), 256, 0, stream>>>(Qb, Kb, Vt, Ab);
  gemm_kernel<2><<<dim3(16, 32), 256, 32768, stream>>>(Ab, wot, out, 4096, 2048, 2048);
}

// Round 8
// 300.704 us; speedup vs baseline: 1.9087x; 1.9087x over previous
//
#include <hip/hip_runtime.h>

typedef unsigned short u16;
using bf16x8 = __attribute__((ext_vector_type(8))) short;
using f32x4  = __attribute__((ext_vector_type(4))) float;

#define ATTN_NEG (-3.0e38f)

__device__ __forceinline__ u16 f2bf_rne(float f) {
  unsigned int u = __float_as_uint(f);
  u += 0x7fffu + ((u >> 16) & 1u);
  return (u16)(u >> 16);
}

__device__ __forceinline__ void load_lds16(const u16* g, u16* l) {
  using gp = const __attribute__((address_space(1))) unsigned int*;
  using lp = __attribute__((address_space(3))) unsigned int*;
  __builtin_amdgcn_global_load_lds((gp)g, (lp)l, 16, 0, 0);
}

// ---------------- fused prep: x convert + 4 weight transposes ----------------
__device__ __forceinline__ void transpose_body(const float* __restrict__ in,
                                               u16* __restrict__ out, int K, int N,
                                               int bx, int by, int tid) {
  __shared__ float tile[32][33];
  int tx = tid & 31, ty = tid >> 5;  // 32 x 8
  int x0 = bx * 32, y0 = by * 32;
  #pragma unroll
  for (int i = 0; i < 32; i += 8)
    tile[ty + i][tx] = in[(size_t)(y0 + ty + i) * N + x0 + tx];
  __syncthreads();
  #pragma unroll
  for (int i = 0; i < 32; i += 8)
    out[(size_t)(x0 + ty + i) * K + y0 + tx] = f2bf_rne(tile[tx][ty + i]);
}

__global__ __launch_bounds__(256) void prep_kernel(const float* __restrict__ x,
                                                   const float* __restrict__ wq,
                                                   const float* __restrict__ wk,
                                                   const float* __restrict__ wv,
                                                   const float* __restrict__ wo,
                                                   u16* xb, u16* wqt, u16* wkt, u16* wvt,
                                                   u16* wot) {
  int bid = blockIdx.x, tid = threadIdx.x;
  if (bid < 8192) {
    int i = bid * 1024 + tid * 4;
    float4 v = *(const float4*)(x + i);
    u16* p = xb + i;
    p[0] = f2bf_rne(v.x); p[1] = f2bf_rne(v.y); p[2] = f2bf_rne(v.z); p[3] = f2bf_rne(v.w);
  } else if (bid < 12288) {
    int t = bid - 8192;
    transpose_body(wq, wqt, 2048, 2048, t & 63, t >> 6, tid);
  } else if (bid < 13312) {
    int t = bid - 12288;
    transpose_body(wk, wkt, 2048, 512, t & 15, t >> 4, tid);
  } else if (bid < 14336) {
    int t = bid - 13312;
    transpose_body(wv, wvt, 2048, 512, t & 15, t >> 4, tid);
  } else {
    int t = bid - 14336;
    transpose_body(wo, wot, 2048, 2048, t & 63, t >> 6, tid);
  }
}

// ---------------- GEMM v2: BK=64 (two m97-layout 32-col halves per step) ----------------
// C[M,N] = A[M,K] * Bt[N,K]^T
// MODE 0: bf16. MODE 1: bf16 transposed k-permuted (V^T). MODE 2: fp32. MODE 3: bf16*kappa (Q).
// LDS: As/Bs each [2 halves][128 rows][32 cols] = 16 KB; half h layout identical to m97.
template <int MODE>
__device__ __forceinline__ void gemm_tile(const u16* __restrict__ A, const u16* __restrict__ Bt,
                                          void* __restrict__ Cv, int M, int N, int K,
                                          int bx, int by, char* smem) {
  u16* As = (u16*)smem;            // [2][128][32]
  u16* Bs = (u16*)(smem + 16384);  // [2][128][32]
  const int tid  = threadIdx.x;
  const int wave = tid >> 6, lane = tid & 63;
  const int quad = lane >> 4, l16 = lane & 15;
  const int m0 = by * 128, n0 = bx * 128;
  const int wm = (wave >> 1) * 64, wn = (wave & 1) * 64;
  f32x4 acc[4][4] = {};

  const int srow = lane >> 2;        // 0..15
  const int scol = (lane & 3) << 3;  // 0,8,16,24

  for (int k0 = 0; k0 < K; k0 += 64) {
    __syncthreads();
    #pragma unroll
    for (int h = 0; h < 2; ++h)
      #pragma unroll
      for (int i = 0; i < 2; ++i) {
        const int row = wave * 16 + i * 64;  // + srow per lane
        load_lds16(A  + (size_t)(m0 + row + srow) * K + k0 + h * 32 + scol,
                   As + h * 4096 + row * 32);
        load_lds16(Bt + (size_t)(n0 + row + srow) * K + k0 + h * 32 + scol,
                   Bs + h * 4096 + row * 32);
      }
    __syncthreads();
    #pragma unroll
    for (int h = 0; h < 2; ++h) {
      bf16x8 af[4], bfr[4];
      #pragma unroll
      for (int i = 0; i < 4; ++i) {
        af[i]  = *(const bf16x8*)(As + h * 4096 + (wm + i * 16 + l16) * 32 + quad * 8);
        bfr[i] = *(const bf16x8*)(Bs + h * 4096 + (wn + i * 16 + l16) * 32 + quad * 8);
      }
      #pragma unroll
      for (int mi = 0; mi < 4; ++mi)
        #pragma unroll
        for (int ni = 0; ni < 4; ++ni)
          acc[mi][ni] =
              __builtin_amdgcn_mfma_f32_16x16x32_bf16(af[mi], bfr[ni], acc[mi][ni], 0, 0, 0);
    }
  }

  if constexpr (MODE == 0 || MODE == 3) {
    const float sc = (MODE == 3) ? 0.12751742f : 1.0f;  // log2(e)/sqrt(128)
    u16* Cb = (u16*)Cv;
    #pragma unroll
    for (int mi = 0; mi < 4; ++mi)
      #pragma unroll
      for (int ni = 0; ni < 4; ++ni) {
        int row = m0 + wm + mi * 16 + quad * 4;
        int col = n0 + wn + ni * 16 + l16;
        #pragma unroll
        for (int r = 0; r < 4; ++r)
          Cb[(size_t)(row + r) * N + col] = f2bf_rne(acc[mi][ni][r] * sc);
      }
  } else if constexpr (MODE == 1) {
    // V^T with k-permuted 32-chunks: pos(k) = ((k&15)>>2)*8 + ((k>>4)&1)*4 + (k&3)
    u16* Cb = (u16*)Cv;
    #pragma unroll
    for (int mi = 0; mi < 4; ++mi)
      #pragma unroll
      for (int ni = 0; ni < 4; ++ni) {
        int col = n0 + wn + ni * 16 + l16;
        #pragma unroll
        for (int r = 0; r < 4; ++r) {
          int row = m0 + wm + mi * 16 + quad * 4 + r;
          int bb = row >> 11, s = row & 2047;
          int c = s & 31;
          int cp = ((c & 15) >> 2) * 8 + ((c >> 4) & 1) * 4 + (c & 3);
          Cb[((size_t)(bb * 512 + col)) * 2048 + (s & ~31) + cp] = f2bf_rne(acc[mi][ni][r]);
        }
      }
  } else {
    float* Cf = (float*)Cv;
    #pragma unroll
    for (int mi = 0; mi < 4; ++mi)
      #pragma unroll
      for (int ni = 0; ni < 4; ++ni) {
        int row = m0 + wm + mi * 16 + quad * 4;
        int col = n0 + wn + ni * 16 + l16;
        #pragma unroll
        for (int r = 0; r < 4; ++r)
          Cf[(size_t)(row + r) * N + col] = acc[mi][ni][r];
      }
  }
}

__global__ __launch_bounds__(256) void qkv_gemm(const u16* xb, const u16* wqt, const u16* wkt,
                                                const u16* wvt, u16* Qb, u16* Kb, u16* Vt) {
  extern __shared__ char smem[];
  int bx = blockIdx.x, by = blockIdx.y;
  if (bx < 16)
    gemm_tile<3>(xb, wqt, Qb, 4096, 2048, 2048, bx, by, smem);
  else if (bx < 20)
    gemm_tile<0>(xb, wkt, Kb, 4096, 512, 2048, bx - 16, by, smem);
  else
    gemm_tile<1>(xb, wvt, Vt, 4096, 512, 2048, bx - 20, by, smem);
}

template <int MODE>
__global__ __launch_bounds__(256) void gemm_kernel(const u16* A, const u16* Bt, void* C,
                                                   int M, int N, int K) {
  extern __shared__ char smem[];
  gemm_tile<MODE>(A, Bt, C, M, N, K, blockIdx.x, blockIdx.y, smem);
}

// ---------------- flash attention: 64-key steps x 32 q-rows/wave ----------------
// R6 proved fat steps amortize the ~860cyc fixed step cost (79.4us). R6's remaining
// dominant term: LDS reads, 256KB/CU-step (~52%). K/V LDS reads are per-wave-step and
// independent of q-rows/wave, so doubling q-rows/wave (R4's lever, proven traffic-wise)
// halves LDS reads per unit work NOW that they dominate. 4 waves x 32 q-rows = 128-row
// tile, two 16-row groups a/b per wave (R2-proven register structure).
//   K sub-layout c,(ks*2+h): slot lane*16B = K[kt0+32c+16h+l16][ks*32+quad*8..+8]
//   V sub-layout c,f:        slot lane*16B = Vt_perm[16f+l16][kt0+32c+quad*8..+8]
// Grid dim3(16,16,2): block (x,h,b) takes tile b?x:15-x; co-resident id/id+256 pairs
// sum to uniform 36 steps (R4/R5-proven balancing). 64.5KB LDS -> 2 blocks/CU.

__device__ __forceinline__ void stage_kv64(const u16* __restrict__ Kg, const u16* __restrict__ Vg,
                                           int kt0, u16* __restrict__ kbuf,
                                           u16* __restrict__ vbuf,
                                           int wave, int quad, int l16) {
  #pragma unroll
  for (int c = 0; c < 2; ++c) {
    #pragma unroll
    for (int h = 0; h < 2; ++h)
      load_lds16(Kg + (size_t)(kt0 + 32 * c + h * 16 + l16) * 512 + wave * 32 + quad * 8,
                 kbuf + c * 4096 + (wave * 2 + h) * 512);
    #pragma unroll
    for (int i = 0; i < 2; ++i) {
      int f = wave * 2 + i;
      load_lds16(Vg + (size_t)(16 * f + l16) * 2048 + kt0 + 32 * c + quad * 8,
                 vbuf + c * 4096 + f * 512);
    }
  }
}

template <bool MASKED>
__device__ __forceinline__ void attn_compute64q2(const u16* __restrict__ kbuf,
                                                 const u16* __restrict__ vbuf,
                                                 int kt0, int q0w, int quad, int l16,
                                                 const bf16x8 (&qfa)[4], const bf16x8 (&qfb)[4],
                                                 f32x4 (&oa)[8], f32x4 (&ob)[8],
                                                 float& la, float& lb) {
  const int slot = (quad * 16 + l16) * 8;  // lane*16B
  #pragma unroll
  for (int c = 0; c < 2; ++c) {
    const int kb = kt0 + 32 * c;
    if (MASKED && kb > q0w + 31) break;  // wave-uniform: subtile above both groups' diagonal

    bf16x8 kf[8];
    #pragma unroll
    for (int kk = 0; kk < 8; ++kk)
      kf[kk] = *(const bf16x8*)(kbuf + c * 4096 + kk * 512 + slot);

    f32x4 sa[2] = {}, sb[2] = {};
    __builtin_amdgcn_s_setprio(1);
    #pragma unroll
    for (int h = 0; h < 2; ++h)
      #pragma unroll
      for (int ks = 0; ks < 4; ++ks) {
        sa[h] = __builtin_amdgcn_mfma_f32_16x16x32_bf16(kf[ks * 2 + h], qfa[ks], sa[h], 0, 0, 0);
        sb[h] = __builtin_amdgcn_mfma_f32_16x16x32_bf16(kf[ks * 2 + h], qfb[ks], sb[h], 0, 0, 0);
      }
    __builtin_amdgcn_s_setprio(0);

    // P packed as x32 A-fragment: element h*4+r sits at contraction slot quad*8+h*4+r,
    // which is exactly perm position cp(k) of k = 16h + quad*4 + r (the Vt layout).
    bf16x8 pca, pcb;
    #pragma unroll
    for (int h = 0; h < 2; ++h)
      #pragma unroll
      for (int r = 0; r < 4; ++r) {
        int kpos = kb + 16 * h + quad * 4 + r;
        float s0 = sa[h][r], s1 = sb[h][r];
        if (MASKED) {
          s0 = (kpos <= q0w + l16) ? s0 : ATTN_NEG;
          s1 = (kpos <= q0w + 16 + l16) ? s1 : ATTN_NEG;
        }
        float p0 = __builtin_amdgcn_exp2f(s0);
        float p1 = __builtin_amdgcn_exp2f(s1);
        la += p0;
        lb += p1;
        pca[h * 4 + r] = (short)f2bf_rne(p0);
        pcb[h * 4 + r] = (short)f2bf_rne(p1);
      }

    __builtin_amdgcn_s_setprio(1);
    #pragma unroll
    for (int f = 0; f < 8; ++f) {
      bf16x8 v8 = *(const bf16x8*)(vbuf + c * 4096 + f * 512 + slot);
      oa[f] = __builtin_amdgcn_mfma_f32_16x16x32_bf16(pca, v8, oa[f], 0, 0, 0);
      ob[f] = __builtin_amdgcn_mfma_f32_16x16x32_bf16(pcb, v8, ob[f], 0, 0, 0);
    }
    __builtin_amdgcn_s_setprio(0);
  }
}

__global__ __launch_bounds__(256, 2) void attn_kernel(const u16* __restrict__ Qb,
                                                      const u16* __restrict__ Kb,
                                                      const u16* __restrict__ Vt,
                                                      u16* __restrict__ Ob) {
  constexpr int S = 2048;
  const int b = blockIdx.z, h = blockIdx.y, g = h >> 2;
  const int tile = b ? blockIdx.x : (15 - blockIdx.x);
  const int tid = threadIdx.x;
  const int wave = tid >> 6, lane = tid & 63, quad = lane >> 4, l16 = lane & 15;
  __shared__ alignas(16) u16 Kt[2][8192];
  __shared__ alignas(16) u16 Vl[2][8192];
  __shared__ float lbuf[4][2][16];

  const u16* Kg = Kb + (size_t)b * S * 512 + g * 128;
  const u16* Vg = Vt + (size_t)(b * 512 + g * 128) * 2048;

  const int q0w = tile * 128 + wave * 32;  // wave's group-a base row (group b = +16)
  const int nsteps = 2 * tile + 2;         // 64-key steps covering 0..128*tile+127

  bf16x8 qfa[4], qfb[4];
  const u16* qra = Qb + (size_t)(b * S + q0w + l16) * 2048 + h * 128 + quad * 8;
  const u16* qrb = qra + (size_t)16 * 2048;
  #pragma unroll
  for (int ks = 0; ks < 4; ++ks) {
    qfa[ks] = *(const bf16x8*)(qra + ks * 32);
    qfb[ks] = *(const bf16x8*)(qrb + ks * 32);
  }

  f32x4 oa[8] = {}, ob[8] = {};
  float la = 0.f, lb = 0.f;

  stage_kv64(Kg, Vg, 0, Kt[0], Vl[0], wave, quad, l16);

  for (int s = 0; s < nsteps; ++s) {
    __syncthreads();  // buf[s&1] staged & visible (compiler drains vmcnt before barrier)
    if (s + 1 < nsteps)
      stage_kv64(Kg, Vg, (s + 1) * 64, Kt[(s + 1) & 1], Vl[(s + 1) & 1], wave, quad, l16);
    if (64 * s + 63 <= q0w)
      attn_compute64q2<false>(Kt[s & 1], Vl[s & 1], s * 64, q0w, quad, l16, qfa, qfb,
                              oa, ob, la, lb);
    else if (64 * s <= q0w + 31)
      attn_compute64q2<true>(Kt[s & 1], Vl[s & 1], s * 64, q0w, quad, l16, qfa, qfb,
                             oa, ob, la, lb);
    // else: fully masked for this wave -> stage+barrier only
  }

  // total l per q=l16: sum over quads
  float lta = la + __shfl_xor(la, 16);
  lta += __shfl_xor(lta, 32);
  float ltb = lb + __shfl_xor(lb, 16);
  ltb += __shfl_xor(ltb, 32);
  if (quad == 0) {
    lbuf[wave][0][l16] = lta;
    lbuf[wave][1][l16] = ltb;
  }
  __builtin_amdgcn_wave_barrier();
  float ila[4], ilb[4];
  #pragma unroll
  for (int r = 0; r < 4; ++r) {
    ila[r] = 1.f / lbuf[wave][0][quad * 4 + r];
    ilb[r] = 1.f / lbuf[wave][1][quad * 4 + r];
  }

  u16* ora = Ob + (size_t)(b * S + q0w + quad * 4) * 2048 + h * 128 + l16;
  u16* orb = ora + (size_t)16 * 2048;
  #pragma unroll
  for (int f = 0; f < 8; ++f)
    #pragma unroll
    for (int r = 0; r < 4; ++r) {
      ora[(size_t)r * 2048 + f * 16] = f2bf_rne(oa[f][r] * ila[r]);
      orb[(size_t)r * 2048 + f * 16] = f2bf_rne(ob[f][r] * ilb[r]);
    }
}

extern "C" void kernel_launch(void* const* d_in, const int* in_sizes, int n_in,
                              void* d_out, int out_size, void* d_ws, size_t ws_size,
                              hipStream_t stream) {
  const float* x  = (const float*)d_in[0];
  const float* wq = (const float*)d_in[1];
  const float* wk = (const float*)d_in[2];
  const float* wv = (const float*)d_in[3];
  const float* wo = (const float*)d_in[4];
  float* out = (float*)d_out;
  char* ws = (char*)d_ws;

  u16* xb  = (u16*)(ws);
  u16* wqt = (u16*)(ws + 16777216);
  u16* wkt = (u16*)(ws + 25165824);
  u16* wvt = (u16*)(ws + 27262976);
  u16* wot = (u16*)(ws + 29360128);
  u16* Qb  = (u16*)(ws + 37748736);
  u16* Kb  = (u16*)(ws + 54525952);
  u16* Vt  = (u16*)(ws + 58720256);
  u16* Ab  = (u16*)(ws + 62914560);

  prep_kernel<<<18432, 256, 0, stream>>>(x, wq, wk, wv, wo, xb, wqt, wkt, wvt, wot);
  qkv_gemm<<<dim3(24, 32), 256, 32768, stream>>>(xb, wqt, wkt, wvt, Qb, Kb, Vt);
  attn_kernel<<<dim3(16, 16, 2), 256, 0, stream>>>(Qb, Kb, Vt, Ab);
  gemm_kernel<2><<<dim3(16, 32), 256, 32768, stream>>>(Ab, wot, out, 4096, 2048, 2048);
}

// Round 9
// 293.912 us; speedup vs baseline: 1.9528x; 1.0231x over previous
//
#include <hip/hip_runtime.h>

typedef unsigned short u16;
using bf16x8 = __attribute__((ext_vector_type(8))) short;
using f32x4  = __attribute__((ext_vector_type(4))) float;

#define ATTN_NEG (-3.0e38f)

__device__ __forceinline__ u16 f2bf_rne(float f) {
  unsigned int u = __float_as_uint(f);
  u += 0x7fffu + ((u >> 16) & 1u);
  return (u16)(u >> 16);
}

__device__ __forceinline__ void load_lds16(const u16* g, u16* l) {
  using gp = const __attribute__((address_space(1))) unsigned int*;
  using lp = __attribute__((address_space(3))) unsigned int*;
  __builtin_amdgcn_global_load_lds((gp)g, (lp)l, 16, 0, 0);
}

// ---------------- fused prep: x convert + 4 weight transposes ----------------
__device__ __forceinline__ void transpose_body(const float* __restrict__ in,
                                               u16* __restrict__ out, int K, int N,
                                               int bx, int by, int tid) {
  __shared__ float tile[32][33];
  int tx = tid & 31, ty = tid >> 5;  // 32 x 8
  int x0 = bx * 32, y0 = by * 32;
  #pragma unroll
  for (int i = 0; i < 32; i += 8)
    tile[ty + i][tx] = in[(size_t)(y0 + ty + i) * N + x0 + tx];
  __syncthreads();
  #pragma unroll
  for (int i = 0; i < 32; i += 8)
    out[(size_t)(x0 + ty + i) * K + y0 + tx] = f2bf_rne(tile[tx][ty + i]);
}

__global__ __launch_bounds__(256) void prep_kernel(const float* __restrict__ x,
                                                   const float* __restrict__ wq,
                                                   const float* __restrict__ wk,
                                                   const float* __restrict__ wv,
                                                   const float* __restrict__ wo,
                                                   u16* xb, u16* wqt, u16* wkt, u16* wvt,
                                                   u16* wot) {
  int bid = blockIdx.x, tid = threadIdx.x;
  if (bid < 8192) {
    int i = bid * 1024 + tid * 4;
    float4 v = *(const float4*)(x + i);
    u16* p = xb + i;
    p[0] = f2bf_rne(v.x); p[1] = f2bf_rne(v.y); p[2] = f2bf_rne(v.z); p[3] = f2bf_rne(v.w);
  } else if (bid < 12288) {
    int t = bid - 8192;
    transpose_body(wq, wqt, 2048, 2048, t & 63, t >> 6, tid);
  } else if (bid < 13312) {
    int t = bid - 12288;
    transpose_body(wk, wkt, 2048, 512, t & 15, t >> 4, tid);
  } else if (bid < 14336) {
    int t = bid - 13312;
    transpose_body(wv, wvt, 2048, 512, t & 15, t >> 4, tid);
  } else {
    int t = bid - 14336;
    transpose_body(wo, wot, 2048, 2048, t & 63, t >> 6, tid);
  }
}

// ---------------- GEMM v2: BK=64 (two m97-layout 32-col halves per step) ----------------
// C[M,N] = A[M,K] * Bt[N,K]^T
// MODE 0: bf16. MODE 1: bf16 transposed k-permuted (V^T). MODE 2: fp32. MODE 3: bf16*kappa (Q).
// LDS: As/Bs each [2 halves][128 rows][32 cols] = 16 KB; half h layout identical to m97.
template <int MODE>
__device__ __forceinline__ void gemm_tile(const u16* __restrict__ A, const u16* __restrict__ Bt,
                                          void* __restrict__ Cv, int M, int N, int K,
                                          int bx, int by, char* smem) {
  u16* As = (u16*)smem;            // [2][128][32]
  u16* Bs = (u16*)(smem + 16384);  // [2][128][32]
  const int tid  = threadIdx.x;
  const int wave = tid >> 6, lane = tid & 63;
  const int quad = lane >> 4, l16 = lane & 15;
  const int m0 = by * 128, n0 = bx * 128;
  const int wm = (wave >> 1) * 64, wn = (wave & 1) * 64;
  f32x4 acc[4][4] = {};

  const int srow = lane >> 2;        // 0..15
  const int scol = (lane & 3) << 3;  // 0,8,16,24

  for (int k0 = 0; k0 < K; k0 += 64) {
    __syncthreads();
    #pragma unroll
    for (int h = 0; h < 2; ++h)
      #pragma unroll
      for (int i = 0; i < 2; ++i) {
        const int row = wave * 16 + i * 64;  // + srow per lane
        load_lds16(A  + (size_t)(m0 + row + srow) * K + k0 + h * 32 + scol,
                   As + h * 4096 + row * 32);
        load_lds16(Bt + (size_t)(n0 + row + srow) * K + k0 + h * 32 + scol,
                   Bs + h * 4096 + row * 32);
      }
    __syncthreads();
    #pragma unroll
    for (int h = 0; h < 2; ++h) {
      bf16x8 af[4], bfr[4];
      #pragma unroll
      for (int i = 0; i < 4; ++i) {
        af[i]  = *(const bf16x8*)(As + h * 4096 + (wm + i * 16 + l16) * 32 + quad * 8);
        bfr[i] = *(const bf16x8*)(Bs + h * 4096 + (wn + i * 16 + l16) * 32 + quad * 8);
      }
      #pragma unroll
      for (int mi = 0; mi < 4; ++mi)
        #pragma unroll
        for (int ni = 0; ni < 4; ++ni)
          acc[mi][ni] =
              __builtin_amdgcn_mfma_f32_16x16x32_bf16(af[mi], bfr[ni], acc[mi][ni], 0, 0, 0);
    }
  }

  if constexpr (MODE == 0 || MODE == 3) {
    const float sc = (MODE == 3) ? 0.12751742f : 1.0f;  // log2(e)/sqrt(128)
    u16* Cb = (u16*)Cv;
    #pragma unroll
    for (int mi = 0; mi < 4; ++mi)
      #pragma unroll
      for (int ni = 0; ni < 4; ++ni) {
        int row = m0 + wm + mi * 16 + quad * 4;
        int col = n0 + wn + ni * 16 + l16;
        #pragma unroll
        for (int r = 0; r < 4; ++r)
          Cb[(size_t)(row + r) * N + col] = f2bf_rne(acc[mi][ni][r] * sc);
      }
  } else if constexpr (MODE == 1) {
    // V^T with k-permuted 32-chunks: pos(k) = ((k&15)>>2)*8 + ((k>>4)&1)*4 + (k&3)
    u16* Cb = (u16*)Cv;
    #pragma unroll
    for (int mi = 0; mi < 4; ++mi)
      #pragma unroll
      for (int ni = 0; ni < 4; ++ni) {
        int col = n0 + wn + ni * 16 + l16;
        #pragma unroll
        for (int r = 0; r < 4; ++r) {
          int row = m0 + wm + mi * 16 + quad * 4 + r;
          int bb = row >> 11, s = row & 2047;
          int c = s & 31;
          int cp = ((c & 15) >> 2) * 8 + ((c >> 4) & 1) * 4 + (c & 3);
          Cb[((size_t)(bb * 512 + col)) * 2048 + (s & ~31) + cp] = f2bf_rne(acc[mi][ni][r]);
        }
      }
  } else {
    float* Cf = (float*)Cv;
    #pragma unroll
    for (int mi = 0; mi < 4; ++mi)
      #pragma unroll
      for (int ni = 0; ni < 4; ++ni) {
        int row = m0 + wm + mi * 16 + quad * 4;
        int col = n0 + wn + ni * 16 + l16;
        #pragma unroll
        for (int r = 0; r < 4; ++r)
          Cf[(size_t)(row + r) * N + col] = acc[mi][ni][r];
      }
  }
}

__global__ __launch_bounds__(256) void qkv_gemm(const u16* xb, const u16* wqt, const u16* wkt,
                                                const u16* wvt, u16* Qb, u16* Kb, u16* Vt) {
  extern __shared__ char smem[];
  int bx = blockIdx.x, by = blockIdx.y;
  if (bx < 16)
    gemm_tile<3>(xb, wqt, Qb, 4096, 2048, 2048, bx, by, smem);
  else if (bx < 20)
    gemm_tile<0>(xb, wkt, Kb, 4096, 512, 2048, bx - 16, by, smem);
  else
    gemm_tile<1>(xb, wvt, Vt, 4096, 512, 2048, bx - 20, by, smem);
}

template <int MODE>
__global__ __launch_bounds__(256) void gemm_kernel(const u16* A, const u16* Bt, void* C,
                                                   int M, int N, int K) {
  extern __shared__ char smem[];
  gemm_tile<MODE>(A, Bt, C, M, N, K, blockIdx.x, blockIdx.y, smem);
}

// ---------------- flash attention: 128-key steps, single-buffer, paired tiles ----------------
// Law from R0-R8: duration = nsteps x ~6000cyc; per-step work is nearly free (R8: 2x work
// = +7%). So: halve steps again. 128 keys/step, R6's balanced pairing (tiles tp & 31-tp,
// uniform pair-sum 17 steps). 64KB K+V tile double-buffered doesn't fit at 2 blocks/CU ->
// SINGLE buffer, two barriers/step: barrier(readers done) -> stage -> barrier(staged) ->
// compute. The lost intra-block overlap is recovered across the 2 co-resident blocks
// (antiphase: one stages while the other computes).
//   K sub-layout c,(ks*2+h): slot lane*16B = K[kt0+32c+16h+l16][ks*32+quad*8..+8]
//   V sub-layout c,f:        slot lane*16B = Vt_perm[16f+l16][kt0+32c+quad*8..+8]

__device__ __forceinline__ void stage_kv128(const u16* __restrict__ Kg,
                                            const u16* __restrict__ Vg, int kt0,
                                            u16* __restrict__ kbuf, u16* __restrict__ vbuf,
                                            int wave, int quad, int l16) {
  #pragma unroll
  for (int c = 0; c < 4; ++c) {
    #pragma unroll
    for (int h = 0; h < 2; ++h)
      load_lds16(Kg + (size_t)(kt0 + 32 * c + h * 16 + l16) * 512 + wave * 32 + quad * 8,
                 kbuf + c * 4096 + (wave * 2 + h) * 512);
    #pragma unroll
    for (int i = 0; i < 2; ++i) {
      int f = wave * 2 + i;
      load_lds16(Vg + (size_t)(16 * f + l16) * 2048 + kt0 + 32 * c + quad * 8,
                 vbuf + c * 4096 + f * 512);
    }
  }
}

template <bool MASKED>
__device__ __forceinline__ void attn_compute128(const u16* __restrict__ kbuf,
                                                const u16* __restrict__ vbuf,
                                                int kt0, int q0w, int quad, int l16,
                                                const bf16x8 (&qf)[4], f32x4 (&o)[8],
                                                float& l_lane) {
  const int slot = (quad * 16 + l16) * 8;  // lane*16B
  #pragma unroll
  for (int c = 0; c < 4; ++c) {
    const int kb = kt0 + 32 * c;
    if (MASKED && kb > q0w + 15) break;  // wave-uniform: sub-tile fully above diagonal

    bf16x8 kf[8];
    #pragma unroll
    for (int kk = 0; kk < 8; ++kk)
      kf[kk] = *(const bf16x8*)(kbuf + c * 4096 + kk * 512 + slot);

    f32x4 sa[2] = {};
    __builtin_amdgcn_s_setprio(1);
    #pragma unroll
    for (int h = 0; h < 2; ++h)
      #pragma unroll
      for (int ks = 0; ks < 4; ++ks)
        sa[h] = __builtin_amdgcn_mfma_f32_16x16x32_bf16(kf[ks * 2 + h], qf[ks], sa[h], 0, 0, 0);
    __builtin_amdgcn_s_setprio(0);

    // P packed as x32 A-fragment: element h*4+r sits at contraction slot quad*8+h*4+r,
    // which is exactly perm position cp(k) of k = 16h + quad*4 + r (the Vt layout).
    bf16x8 pc;
    #pragma unroll
    for (int h = 0; h < 2; ++h)
      #pragma unroll
      for (int r = 0; r < 4; ++r) {
        float s = sa[h][r];
        if (MASKED) {
          int kpos = kb + 16 * h + quad * 4 + r;
          s = (kpos <= q0w + l16) ? s : ATTN_NEG;
        }
        float p = __builtin_amdgcn_exp2f(s);
        l_lane += p;
        pc[h * 4 + r] = (short)f2bf_rne(p);
      }

    __builtin_amdgcn_s_setprio(1);
    #pragma unroll
    for (int f = 0; f < 8; ++f) {
      bf16x8 v8 = *(const bf16x8*)(vbuf + c * 4096 + f * 512 + slot);
      o[f] = __builtin_amdgcn_mfma_f32_16x16x32_bf16(pc, v8, o[f], 0, 0, 0);
    }
    __builtin_amdgcn_s_setprio(0);
  }
}

// Blocks: (pair 0..15, head, b); 4 waves x 16 q-rows = 64-row tiles; pair p does tiles p
// and 31-p -> uniform 17 128-key steps; 512 blocks = 2 blocks/CU.
__global__ __launch_bounds__(256, 2) void attn_kernel(const u16* __restrict__ Qb,
                                                      const u16* __restrict__ Kb,
                                                      const u16* __restrict__ Vt,
                                                      u16* __restrict__ Ob) {
  constexpr int S = 2048;
  const int b = blockIdx.z, h = blockIdx.y, g = h >> 2, tp = blockIdx.x;
  const int tid = threadIdx.x;
  const int wave = tid >> 6, lane = tid & 63, quad = lane >> 4, l16 = lane & 15;
  __shared__ alignas(16) u16 Kt[4][4096];  // one 128-key K tile
  __shared__ alignas(16) u16 Vl[4][4096];  // one 128-key V tile
  __shared__ float lbuf[4][16];

  const u16* Kg = Kb + (size_t)b * S * 512 + g * 128;
  const u16* Vg = Vt + (size_t)(b * 512 + g * 128) * 2048;

  #pragma unroll
  for (int half = 0; half < 2; ++half) {
    const int tile = (half == 0) ? tp : 31 - tp;
    const int wrow = (half == 0) ? wave : 3 - wave;  // balance diag-step partial work
    const int q0w = tile * 64 + wrow * 16;
    const int nsteps = (tile + 2) >> 1;  // 128-key steps

    bf16x8 qf[4];
    const u16* qrow = Qb + (size_t)(b * S + q0w + l16) * 2048 + h * 128 + quad * 8;
    #pragma unroll
    for (int ks = 0; ks < 4; ++ks) qf[ks] = *(const bf16x8*)(qrow + ks * 32);

    f32x4 o[8] = {};
    float l_lane = 0.f;

    for (int s = 0; s < nsteps; ++s) {
      __syncthreads();  // all waves done reading the buffer (prev step / prev half)
      stage_kv128(Kg, Vg, s * 128, Kt[0], Vl[0], wave, quad, l16);
      __syncthreads();  // stage complete & visible (compiler drains vmcnt before barrier)
      if (128 * s + 127 <= q0w)
        attn_compute128<false>(Kt[0], Vl[0], s * 128, q0w, quad, l16, qf, o, l_lane);
      else if (128 * s <= q0w + 15)
        attn_compute128<true>(Kt[0], Vl[0], s * 128, q0w, quad, l16, qf, o, l_lane);
      // else: fully masked for this wave -> barriers only
    }

    // total l per q=l16: sum over quads
    float lt = l_lane + __shfl_xor(l_lane, 16);
    lt += __shfl_xor(lt, 32);
    if (quad == 0) lbuf[wave][l16] = lt;
    __builtin_amdgcn_wave_barrier();
    float il[4];
    #pragma unroll
    for (int r = 0; r < 4; ++r) il[r] = 1.f / lbuf[wave][quad * 4 + r];

    u16* orow = Ob + (size_t)(b * S + q0w + quad * 4) * 2048 + h * 128 + l16;
    #pragma unroll
    for (int f = 0; f < 8; ++f)
      #pragma unroll
      for (int r = 0; r < 4; ++r)
        orow[(size_t)r * 2048 + f * 16] = f2bf_rne(o[f][r] * il[r]);
  }
}

extern "C" void kernel_launch(void* const* d_in, const int* in_sizes, int n_in,
                              void* d_out, int out_size, void* d_ws, size_t ws_size,
                              hipStream_t stream) {
  const float* x  = (const float*)d_in[0];
  const float* wq = (const float*)d_in[1];
  const float* wk = (const float*)d_in[2];
  const float* wv = (const float*)d_in[3];
  const float* wo = (const float*)d_in[4];
  float* out = (float*)d_out;
  char* ws = (char*)d_ws;

  u16* xb  = (u16*)(ws);
  u16* wqt = (u16*)(ws + 16777216);
  u16* wkt = (u16*)(ws + 25165824);
  u16* wvt = (u16*)(ws + 27262976);
  u16* wot = (u16*)(ws + 29360128);
  u16* Qb  = (u16*)(ws + 37748736);
  u16* Kb  = (u16*)(ws + 54525952);
  u16* Vt  = (u16*)(ws + 58720256);
  u16* Ab  = (u16*)(ws + 62914560);

  prep_kernel<<<18432, 256, 0, stream>>>(x, wq, wk, wv, wo, xb, wqt, wkt, wvt, wot);
  qkv_gemm<<<dim3(24, 32), 256, 32768, stream>>>(xb, wqt, wkt, wvt, Qb, Kb, Vt);
  attn_kernel<<<dim3(16, 16, 2), 256, 0, stream>>>(Qb, Kb, Vt, Ab);
  gemm_kernel<2><<<dim3(16, 32), 256, 32768, stream>>>(Ab, wot, out, 4096, 2048, 2048);
}

// Round 10
// 290.239 us; speedup vs baseline: 1.9775x; 1.0127x over previous
//
#include <hip/hip_runtime.h>

typedef unsigned short u16;
using bf16x8 = __attribute__((ext_vector_type(8))) short;
using f32x4  = __attribute__((ext_vector_type(4))) float;

#define ATTN_NEG (-3.0e38f)

__device__ __forceinline__ u16 f2bf_rne(float f) {
  unsigned int u = __float_as_uint(f);
  u += 0x7fffu + ((u >> 16) & 1u);
  return (u16)(u >> 16);
}

__device__ __forceinline__ void load_lds16(const u16* g, u16* l) {
  using gp = const __attribute__((address_space(1))) unsigned int*;
  using lp = __attribute__((address_space(3))) unsigned int*;
  __builtin_amdgcn_global_load_lds((gp)g, (lp)l, 16, 0, 0);
}

// ---------------- fused prep: x convert + 4 weight transposes ----------------
__device__ __forceinline__ void transpose_body(const float* __restrict__ in,
                                               u16* __restrict__ out, int K, int N,
                                               int bx, int by, int tid) {
  __shared__ float tile[32][33];
  int tx = tid & 31, ty = tid >> 5;  // 32 x 8
  int x0 = bx * 32, y0 = by * 32;
  #pragma unroll
  for (int i = 0; i < 32; i += 8)
    tile[ty + i][tx] = in[(size_t)(y0 + ty + i) * N + x0 + tx];
  __syncthreads();
  #pragma unroll
  for (int i = 0; i < 32; i += 8)
    out[(size_t)(x0 + ty + i) * K + y0 + tx] = f2bf_rne(tile[tx][ty + i]);
}

__global__ __launch_bounds__(256) void prep_kernel(const float* __restrict__ x,
                                                   const float* __restrict__ wq,
                                                   const float* __restrict__ wk,
                                                   const float* __restrict__ wv,
                                                   const float* __restrict__ wo,
                                                   u16* xb, u16* wqt, u16* wkt, u16* wvt,
                                                   u16* wot) {
  int bid = blockIdx.x, tid = threadIdx.x;
  if (bid < 8192) {
    int i = bid * 1024 + tid * 4;
    float4 v = *(const float4*)(x + i);
    u16* p = xb + i;
    p[0] = f2bf_rne(v.x); p[1] = f2bf_rne(v.y); p[2] = f2bf_rne(v.z); p[3] = f2bf_rne(v.w);
  } else if (bid < 12288) {
    int t = bid - 8192;
    transpose_body(wq, wqt, 2048, 2048, t & 63, t >> 6, tid);
  } else if (bid < 13312) {
    int t = bid - 12288;
    transpose_body(wk, wkt, 2048, 512, t & 15, t >> 4, tid);
  } else if (bid < 14336) {
    int t = bid - 13312;
    transpose_body(wv, wvt, 2048, 512, t & 15, t >> 4, tid);
  } else {
    int t = bid - 14336;
    transpose_body(wo, wot, 2048, 2048, t & 63, t >> 6, tid);
  }
}

// ---------------- GEMM v2: BK=64 (two m97-layout 32-col halves per step) ----------------
// C[M,N] = A[M,K] * Bt[N,K]^T
// MODE 0: bf16. MODE 1: bf16 transposed k-permuted (V^T). MODE 2: fp32. MODE 3: bf16*kappa (Q).
// LDS: As/Bs each [2 halves][128 rows][32 cols] = 16 KB; half h layout identical to m97.
template <int MODE>
__device__ __forceinline__ void gemm_tile(const u16* __restrict__ A, const u16* __restrict__ Bt,
                                          void* __restrict__ Cv, int M, int N, int K,
                                          int bx, int by, char* smem) {
  u16* As = (u16*)smem;            // [2][128][32]
  u16* Bs = (u16*)(smem + 16384);  // [2][128][32]
  const int tid  = threadIdx.x;
  const int wave = tid >> 6, lane = tid & 63;
  const int quad = lane >> 4, l16 = lane & 15;
  const int m0 = by * 128, n0 = bx * 128;
  const int wm = (wave >> 1) * 64, wn = (wave & 1) * 64;
  f32x4 acc[4][4] = {};

  const int srow = lane >> 2;        // 0..15
  const int scol = (lane & 3) << 3;  // 0,8,16,24

  for (int k0 = 0; k0 < K; k0 += 64) {
    __syncthreads();
    #pragma unroll
    for (int h = 0; h < 2; ++h)
      #pragma unroll
      for (int i = 0; i < 2; ++i) {
        const int row = wave * 16 + i * 64;  // + srow per lane
        load_lds16(A  + (size_t)(m0 + row + srow) * K + k0 + h * 32 + scol,
                   As + h * 4096 + row * 32);
        load_lds16(Bt + (size_t)(n0 + row + srow) * K + k0 + h * 32 + scol,
                   Bs + h * 4096 + row * 32);
      }
    __syncthreads();
    #pragma unroll
    for (int h = 0; h < 2; ++h) {
      bf16x8 af[4], bfr[4];
      #pragma unroll
      for (int i = 0; i < 4; ++i) {
        af[i]  = *(const bf16x8*)(As + h * 4096 + (wm + i * 16 + l16) * 32 + quad * 8);
        bfr[i] = *(const bf16x8*)(Bs + h * 4096 + (wn + i * 16 + l16) * 32 + quad * 8);
      }
      #pragma unroll
      for (int mi = 0; mi < 4; ++mi)
        #pragma unroll
        for (int ni = 0; ni < 4; ++ni)
          acc[mi][ni] =
              __builtin_amdgcn_mfma_f32_16x16x32_bf16(af[mi], bfr[ni], acc[mi][ni], 0, 0, 0);
    }
  }

  if constexpr (MODE == 0 || MODE == 3) {
    const float sc = (MODE == 3) ? 0.12751742f : 1.0f;  // log2(e)/sqrt(128)
    u16* Cb = (u16*)Cv;
    #pragma unroll
    for (int mi = 0; mi < 4; ++mi)
      #pragma unroll
      for (int ni = 0; ni < 4; ++ni) {
        int row = m0 + wm + mi * 16 + quad * 4;
        int col = n0 + wn + ni * 16 + l16;
        #pragma unroll
        for (int r = 0; r < 4; ++r)
          Cb[(size_t)(row + r) * N + col] = f2bf_rne(acc[mi][ni][r] * sc);
      }
  } else if constexpr (MODE == 1) {
    // V^T with k-permuted 32-chunks: pos(k) = ((k&15)>>2)*8 + ((k>>4)&1)*4 + (k&3)
    u16* Cb = (u16*)Cv;
    #pragma unroll
    for (int mi = 0; mi < 4; ++mi)
      #pragma unroll
      for (int ni = 0; ni < 4; ++ni) {
        int col = n0 + wn + ni * 16 + l16;
        #pragma unroll
        for (int r = 0; r < 4; ++r) {
          int row = m0 + wm + mi * 16 + quad * 4 + r;
          int bb = row >> 11, s = row & 2047;
          int c = s & 31;
          int cp = ((c & 15) >> 2) * 8 + ((c >> 4) & 1) * 4 + (c & 3);
          Cb[((size_t)(bb * 512 + col)) * 2048 + (s & ~31) + cp] = f2bf_rne(acc[mi][ni][r]);
        }
      }
  } else {
    float* Cf = (float*)Cv;
    #pragma unroll
    for (int mi = 0; mi < 4; ++mi)
      #pragma unroll
      for (int ni = 0; ni < 4; ++ni) {
        int row = m0 + wm + mi * 16 + quad * 4;
        int col = n0 + wn + ni * 16 + l16;
        #pragma unroll
        for (int r = 0; r < 4; ++r)
          Cf[(size_t)(row + r) * N + col] = acc[mi][ni][r];
      }
  }
}

// T1 bijective XCD-chunked swizzle (nwg % 8 == 0): each XCD gets a contiguous wg range
// -> contiguous by-band -> A-panels L2-resident per XCD.
__global__ __launch_bounds__(256) void qkv_gemm(const u16* xb, const u16* wqt, const u16* wkt,
                                                const u16* wvt, u16* Qb, u16* Kb, u16* Vt) {
  extern __shared__ char smem[];
  const int wg = (blockIdx.x & 7) * 96 + (blockIdx.x >> 3);  // nwg=768, 96 per XCD
  const int bx = wg % 24, by = wg / 24;
  if (bx < 16)
    gemm_tile<3>(xb, wqt, Qb, 4096, 2048, 2048, bx, by, smem);
  else if (bx < 20)
    gemm_tile<0>(xb, wkt, Kb, 4096, 512, 2048, bx - 16, by, smem);
  else
    gemm_tile<1>(xb, wvt, Vt, 4096, 512, 2048, bx - 20, by, smem);
}

template <int MODE>
__global__ __launch_bounds__(256) void gemm_kernel(const u16* A, const u16* Bt, void* C,
                                                   int M, int N, int K) {
  extern __shared__ char smem[];
  const int cpx = gridDim.x >> 3;
  const int wg = (blockIdx.x & 7) * cpx + (blockIdx.x >> 3);
  const int nbx = N >> 7;
  gemm_tile<MODE>(A, Bt, C, M, N, K, wg % nbx, wg / nbx, smem);
}

// ---------------- flash attention: 64-key steps, XCD-pinned K/V ----------------
// R6's proven 79.4us kernel verbatim; only the grid decode changes. Flat 512 blocks with
// id&7 = b*4+g: hardware round-robins blockIdx%8 -> XCD, and there are exactly 8 (b,g)
// groups, so every block on XCD x stages only group-x's K+V (1 MB -> fits the 4 MB
// per-XCD L2). Previously the 64 blocks per group were spread across all 8 XCDs and the
// (non-cross-coherent) L2s each refetched from L3 -> staging supply was the ~5.8k
// cyc/unit limiter (R6/R8/R9 invariant).
//   K sub-layout c,(ks*2+h): slot lane*16B = K[kt0+32c+16h+l16][ks*32+quad*8..+8]
//   V sub-layout c,f:        slot lane*16B = Vt_perm[16f+l16][kt0+32c+quad*8..+8]

__device__ __forceinline__ void stage_kv64(const u16* __restrict__ Kg, const u16* __restrict__ Vg,
                                           int kt0, u16* __restrict__ kbuf,
                                           u16* __restrict__ vbuf,
                                           int wave, int quad, int l16) {
  #pragma unroll
  for (int c = 0; c < 2; ++c) {
    #pragma unroll
    for (int h = 0; h < 2; ++h)
      load_lds16(Kg + (size_t)(kt0 + 32 * c + h * 16 + l16) * 512 + wave * 32 + quad * 8,
                 kbuf + c * 4096 + (wave * 2 + h) * 512);
    #pragma unroll
    for (int i = 0; i < 2; ++i) {
      int f = wave * 2 + i;
      load_lds16(Vg + (size_t)(16 * f + l16) * 2048 + kt0 + 32 * c + quad * 8,
                 vbuf + c * 4096 + f * 512);
    }
  }
}

template <bool MASKED>
__device__ __forceinline__ void attn_compute64(const u16* __restrict__ kbuf,
                                               const u16* __restrict__ vbuf,
                                               int kt0, int q0w, int quad, int l16,
                                               const bf16x8 (&qf)[4], f32x4 (&o)[8],
                                               float& l_lane) {
  const int slot = (quad * 16 + l16) * 8;  // lane*16B
  #pragma unroll
  for (int c = 0; c < 2; ++c) {
    const int kb = kt0 + 32 * c;
    if (MASKED && kb > q0w + 15) break;  // wave-uniform: sub-tile fully above diagonal

    bf16x8 kf[8];
    #pragma unroll
    for (int kk = 0; kk < 8; ++kk)
      kf[kk] = *(const bf16x8*)(kbuf + c * 4096 + kk * 512 + slot);

    f32x4 sa[2] = {};
    __builtin_amdgcn_s_setprio(1);
    #pragma unroll
    for (int h = 0; h < 2; ++h)
      #pragma unroll
      for (int ks = 0; ks < 4; ++ks)
        sa[h] = __builtin_amdgcn_mfma_f32_16x16x32_bf16(kf[ks * 2 + h], qf[ks], sa[h], 0, 0, 0);
    __builtin_amdgcn_s_setprio(0);

    // P packed as x32 A-fragment: element h*4+r sits at contraction slot quad*8+h*4+r,
    // which is exactly perm position cp(k) of k = 16h + quad*4 + r (the Vt layout).
    bf16x8 pc;
    #pragma unroll
    for (int h = 0; h < 2; ++h)
      #pragma unroll
      for (int r = 0; r < 4; ++r) {
        float s = sa[h][r];
        if (MASKED) {
          int kpos = kb + 16 * h + quad * 4 + r;
          s = (kpos <= q0w + l16) ? s : ATTN_NEG;
        }
        float p = __builtin_amdgcn_exp2f(s);
        l_lane += p;
        pc[h * 4 + r] = (short)f2bf_rne(p);
      }

    __builtin_amdgcn_s_setprio(1);
    #pragma unroll
    for (int f = 0; f < 8; ++f) {
      bf16x8 v8 = *(const bf16x8*)(vbuf + c * 4096 + f * 512 + slot);
      o[f] = __builtin_amdgcn_mfma_f32_16x16x32_bf16(pc, v8, o[f], 0, 0, 0);
    }
    __builtin_amdgcn_s_setprio(0);
  }
}

// Flat 512 blocks: id&7 = b*4+g (XCD pin), id>>3 = j: tp = j&15, head = g*4 + (j>>4).
// 4 waves x 16 q-rows = 64-row tiles; block does tiles tp and 31-tp -> uniform 33 steps;
// 2 blocks/CU.
__global__ __launch_bounds__(256, 2) void attn_kernel(const u16* __restrict__ Qb,
                                                      const u16* __restrict__ Kb,
                                                      const u16* __restrict__ Vt,
                                                      u16* __restrict__ Ob) {
  constexpr int S = 2048;
  const int id = blockIdx.x;
  const int b = (id >> 2) & 1, g = id & 3;
  const int j = id >> 3;
  const int tp = j & 15, h = g * 4 + (j >> 4);
  const int tid = threadIdx.x;
  const int wave = tid >> 6, lane = tid & 63, quad = lane >> 4, l16 = lane & 15;
  __shared__ alignas(16) u16 Kt[2][8192];
  __shared__ alignas(16) u16 Vl[2][8192];
  __shared__ float lbuf[4][16];

  const u16* Kg = Kb + (size_t)b * S * 512 + g * 128;
  const u16* Vg = Vt + (size_t)(b * 512 + g * 128) * 2048;

  #pragma unroll
  for (int half = 0; half < 2; ++half) {
    const int tile = (half == 0) ? tp : 31 - tp;
    const int wrow = (half == 0) ? wave : 3 - wave;  // balance diag-step partial work
    const int q0w = tile * 64 + wrow * 16;
    const int nsteps = tile + 1;  // 64-key steps

    bf16x8 qf[4];
    const u16* qrow = Qb + (size_t)(b * S + q0w + l16) * 2048 + h * 128 + quad * 8;
    #pragma unroll
    for (int ks = 0; ks < 4; ++ks) qf[ks] = *(const bf16x8*)(qrow + ks * 32);

    f32x4 o[8] = {};
    float l_lane = 0.f;

    __syncthreads();  // previous half's readers done before re-staging buf0
    stage_kv64(Kg, Vg, 0, Kt[0], Vl[0], wave, quad, l16);

    for (int s = 0; s < nsteps; ++s) {
      __syncthreads();  // buf[s&1] staged & visible (compiler drains vmcnt before barrier)
      if (s + 1 < nsteps)
        stage_kv64(Kg, Vg, (s + 1) * 64, Kt[(s + 1) & 1], Vl[(s + 1) & 1], wave, quad, l16);
      if (s + 1 < nsteps)
        attn_compute64<false>(Kt[s & 1], Vl[s & 1], s * 64, q0w, quad, l16, qf, o, l_lane);
      else
        attn_compute64<true>(Kt[s & 1], Vl[s & 1], s * 64, q0w, quad, l16, qf, o, l_lane);
    }

    // total l per q=l16: sum over quads
    float lt = l_lane + __shfl_xor(l_lane, 16);
    lt += __shfl_xor(lt, 32);
    if (quad == 0) lbuf[wave][l16] = lt;
    __builtin_amdgcn_wave_barrier();
    float il[4];
    #pragma unroll
    for (int r = 0; r < 4; ++r) il[r] = 1.f / lbuf[wave][quad * 4 + r];

    u16* orow = Ob + (size_t)(b * S + q0w + quad * 4) * 2048 + h * 128 + l16;
    #pragma unroll
    for (int f = 0; f < 8; ++f)
      #pragma unroll
      for (int r = 0; r < 4; ++r)
        orow[(size_t)r * 2048 + f * 16] = f2bf_rne(o[f][r] * il[r]);
  }
}

extern "C" void kernel_launch(void* const* d_in, const int* in_sizes, int n_in,
                              void* d_out, int out_size, void* d_ws, size_t ws_size,
                              hipStream_t stream) {
  const float* x  = (const float*)d_in[0];
  const float* wq = (const float*)d_in[1];
  const float* wk = (const float*)d_in[2];
  const float* wv = (const float*)d_in[3];
  const float* wo = (const float*)d_in[4];
  float* out = (float*)d_out;
  char* ws = (char*)d_ws;

  u16* xb  = (u16*)(ws);
  u16* wqt = (u16*)(ws + 16777216);
  u16* wkt = (u16*)(ws + 25165824);
  u16* wvt = (u16*)(ws + 27262976);
  u16* wot = (u16*)(ws + 29360128);
  u16* Qb  = (u16*)(ws + 37748736);
  u16* Kb  = (u16*)(ws + 54525952);
  u16* Vt  = (u16*)(ws + 58720256);
  u16* Ab  = (u16*)(ws + 62914560);

  prep_kernel<<<18432, 256, 0, stream>>>(x, wq, wk, wv, wo, xb, wqt, wkt, wvt, wot);
  qkv_gemm<<<768, 256, 32768, stream>>>(xb, wqt, wkt, wvt, Qb, Kb, Vt);
  attn_kernel<<<512, 256, 0, stream>>>(Qb, Kb, Vt, Ab);
  gemm_kernel<2><<<512, 256, 32768, stream>>>(Ab, wot, out, 4096, 2048, 2048);
}